// Round 10
// baseline (353.776 us; speedup 1.0000x reference)
//
#include <hip/hip_runtime.h>
#include <hip/hip_bf16.h>
#include <hip/hip_fp16.h>
#include <math.h>

#define NF     128
#define HID    6
#define NC     10
#define NG     64
#define SLOTS  64     // ELL row capacity (deg ~ Poisson(32); P(deg>64) ~ 4e-7/node)
#define OVFCAP 8192

// bucket build params: 512-node buckets for the scatter (few reserve atomics),
// 128-node subranges for the ELL build (fits 32KB LDS tile).
#define BKT_SH    9
#define BKT_NODES 512
#define NBK_MAX   256      // supports N <= 131072
#define SUB_SH    7
#define SUB_NODES 128
#define EPB       4096     // edges per phase-1 block (256 thr x 16)
#define BCAP      18432    // per-bucket capacity (mean 16384, +16 sigma)
#define BOVFCAP   4096

// g row: 6 values as fp16, padded to 16B (8 halves) -> ONE dwordx4 per neighbor.
__device__ __forceinline__ void addh2(__half2& a0, __half2& a1, __half2& a2, uint4 q) {
    const __half2* h = (const __half2*)&q;
    a0 = __hadd2(a0, h[0]);
    a1 = __hadd2(a1, h[1]);
    a2 = __hadd2(a2, h[2]);
}

__device__ __forceinline__ __half2 shfl_xor_h2(__half2 v, int m) {
    union { __half2 h; unsigned int u; } a;
    a.h = v;
    a.u = __shfl_xor(a.u, m);
    return a.h;
}

__device__ __forceinline__ uint4 packh(const float* v) {
    uint4 q;
    __half2* h = (__half2*)&q;
    h[0] = __floats2half2_rn(v[0], v[1]);
    h[1] = __floats2half2_rn(v[2], v[3]);
    h[2] = __floats2half2_rn(v[4], v[5]);
    h[3] = __floats2half2_rn(0.f, 0.f);
    return q;
}

// ---------------- phase 1: bin edges by dst>>9, rank-from-count, binary-search copy-out ----------------
__global__ __launch_bounds__(256) void bucket_scatter_kernel(
        const int* __restrict__ src, const int* __restrict__ dst, int E, int nbk,
        int* __restrict__ bucket_cursor, unsigned int* __restrict__ bucket_arr,
        int* __restrict__ bovf_meta, int2* __restrict__ bovf) {
    __shared__ int cntL[NBK_MAX];
    __shared__ int offs[NBK_MAX + 1];
    __shared__ int gb[NBK_MAX];
    __shared__ int wtot[4];
    __shared__ unsigned int stage[EPB];
    int tid = threadIdx.x;
    if (tid < NBK_MAX) cntL[tid] = 0;
    __syncthreads();                                     // B1
    int e0 = blockIdx.x * EPB;
    int cnt_e = E - e0; if (cnt_e > EPB) cnt_e = EPB;
    int sreg[16], dreg[16], rank[16];
    // pass A: load edges + LDS-atomic rank (atomic return IS the local rank)
    if (cnt_e == EPB && (E & 3) == 0) {
        const int4* s4p = (const int4*)(src + e0);
        const int4* d4p = (const int4*)(dst + e0);
#pragma unroll
        for (int k = 0; k < 4; ++k) {
            int4 sv = s4p[k * 256 + tid];
            int4 dv = d4p[k * 256 + tid];
            sreg[4*k+0] = sv.x; sreg[4*k+1] = sv.y; sreg[4*k+2] = sv.z; sreg[4*k+3] = sv.w;
            dreg[4*k+0] = dv.x; dreg[4*k+1] = dv.y; dreg[4*k+2] = dv.z; dreg[4*k+3] = dv.w;
        }
#pragma unroll
        for (int k = 0; k < 16; ++k) rank[k] = atomicAdd(&cntL[dreg[k] >> BKT_SH], 1);
    } else {
#pragma unroll
        for (int k = 0; k < 16; ++k) {
            int e = e0 + k * 256 + tid;
            if (e < E) {
                dreg[k] = dst[e]; sreg[k] = src[e];
                rank[k] = atomicAdd(&cntL[dreg[k] >> BKT_SH], 1);
            } else dreg[k] = -1;
        }
    }
    __syncthreads();                                     // B2
    // exclusive scan over 256 bucket counts: 1/thread wave shfl-scan + wave-total combine
    int lane = tid & 63, wv = tid >> 6;
    int c = cntL[tid];
    int v = c;
#pragma unroll
    for (int off = 1; off < 64; off <<= 1) {
        int u = __shfl_up(v, off);
        if (lane >= off) v += u;
    }
    if (lane == 63) wtot[wv] = v;
    __syncthreads();                                     // B3
    int wbase = 0;
    for (int w = 0; w < wv; ++w) wbase += wtot[w];
    int ex = wbase + v - c;
    offs[tid] = ex;
    if (tid == 0) offs[NBK_MAX] = cnt_e;                 // sentinel
    // reserve global spans (one atomic per non-empty bucket per block; nbk ~196)
    if (tid < nbk && c > 0) gb[tid] = atomicAdd(&bucket_cursor[tid], c);
    __syncthreads();                                     // B4
    // pass B: direct-placed stage write (no second atomic)
#pragma unroll
    for (int k = 0; k < 16; ++k) {
        int d = dreg[k];
        if (d < 0) continue;
        int b = d >> BKT_SH;
        stage[offs[b] + rank[k]] =
            (unsigned int)(d & (BKT_NODES - 1)) | ((unsigned int)sreg[k] << BKT_SH);
    }
    __syncthreads();                                     // B5
    // copy out: bucket via binary search on offs (runs -> coalesced segments)
    for (int j = tid; j < cnt_e; j += 256) {
        unsigned int p = stage[j];
        int lo = 0, hi = NBK_MAX;
        while (hi - lo > 1) {
            int mid = (lo + hi) >> 1;
            if (offs[mid] <= j) lo = mid; else hi = mid;
        }
        int b = lo;
        int grel = gb[b] + (j - offs[b]);
        if (grel < BCAP) {
            bucket_arr[(size_t)b * BCAP + grel] = p;
        } else {  // bucket capacity overflow (~never)
            int d = (b << BKT_SH) | (int)(p & (BKT_NODES - 1));
            int s = (int)(p >> BKT_SH);
            int p2 = atomicAdd(bovf_meta, 1);
            if (p2 < BOVFCAP) bovf[p2] = make_int2(d, s);
        }
    }
}

// ---------------- phase 2: ELL build, one block per 128-node subrange ----------------
// Scans the parent 512-bucket's edges, filters to its quarter. Rows padded with
// sentinel N (zero row in g) so gathers add int4 chunks unconditionally.
__global__ __launch_bounds__(256) void ell_build_kernel(
        const unsigned int* __restrict__ bucket_arr, const int* __restrict__ bucket_cursor,
        const int* __restrict__ bovf_meta, const int2* __restrict__ bovf,
        int* __restrict__ ell, int* __restrict__ cnt, float* __restrict__ dinv,
        int* __restrict__ ovf_meta, int* __restrict__ ovf_dst, int* __restrict__ ovf_src,
        int N) {
    __shared__ int ell_s[SUB_NODES * SLOTS];   // 32KB
    __shared__ int cur[SUB_NODES];
    int b = blockIdx.x;              // 128-node subrange index
    int pb = b >> 2;                 // parent 512-bucket
    int subq = b & 3;                // which quarter
    int tid = threadIdx.x;
    if (tid < SUB_NODES) cur[tid] = 0;
    for (int k = tid; k < SUB_NODES * SLOTS; k += 256) ell_s[k] = N;   // sentinel pad
    __syncthreads();
    int bc = bucket_cursor[pb];
    if (bc > BCAP) bc = BCAP;
    const unsigned int* ba = bucket_arr + (size_t)pb * BCAP;
    int rlo = subq << SUB_SH;        // local node range [rlo, rlo+128) within bucket
    for (int j = tid; j < bc; j += 256) {
        unsigned int p = ba[j];
        int r = (int)(p & (BKT_NODES - 1));
        if ((r >> SUB_SH) != subq) continue;
        int s = (int)(p >> BKT_SH);
        int rl = r & (SUB_NODES - 1);
        int slot = atomicAdd(&cur[rl], 1);
        if (slot < SLOTS) {
            ell_s[rl * SLOTS + slot] = s;
        } else {  // node degree overflow (~never)
            int d = (b << SUB_SH) + rl;
            int q = atomicAdd(ovf_meta, 1);
            if (q < OVFCAP) { ovf_dst[q] = d; ovf_src[q] = s; }
        }
    }
    // fold in bucket-capacity overflow edges (list is ~always empty)
    int m = *bovf_meta;
    if (m > BOVFCAP) m = BOVFCAP;
    for (int t = tid; t < m; t += 256) {
        int2 e = bovf[t];
        if ((e.x >> SUB_SH) == b) {
            int rl = e.x & (SUB_NODES - 1);
            int slot = atomicAdd(&cur[rl], 1);
            if (slot < SLOTS) {
                ell_s[rl * SLOTS + slot] = e.y;
            } else {
                int q = atomicAdd(ovf_meta, 1);
                if (q < OVFCAP) { ovf_dst[q] = e.x; ovf_src[q] = e.y; }
            }
        }
    }
    __syncthreads();
    int nid0 = b << SUB_SH;
    int rows = N - nid0; if (rows > SUB_NODES) rows = SUB_NODES;
    if (rows <= 0) return;
    int4* eg = (int4*)(ell + (size_t)nid0 * SLOTS);
    const int4* es = (const int4*)ell_s;
    // dump only occupied int4 chunks (gathers never read past ceil(cnt/4) chunks)
    for (int k = tid; k < rows * (SLOTS / 4); k += 256) {
        int r = k >> 4;            // SLOTS/4 == 16 chunks per row
        int q = k & 15;
        int c = cur[r]; if (c > SLOTS) c = SLOTS;
        if (q * 4 < c) eg[k] = es[k];
    }
    for (int r = tid; r < rows; r += 256) {
        int deg = cur[r];
        cnt[nid0 + r] = deg;
        dinv[nid0 + r] = rsqrtf((float)deg + 1.0f);   // +1 self loop
    }
}

// ---------------- layer 1: g = dinv * (x @ W1), 8 lanes per node, fp16 row out ----------------
__global__ __launch_bounds__(256) void layer1_kernel(const float* __restrict__ x,
                                                     const float* __restrict__ W,
                                                     const float* __restrict__ dinv,
                                                     uint4* __restrict__ g16, int N) {
    __shared__ float sW[8 * 100];
    for (int idx = threadIdx.x; idx < NF * HID; idx += 256) {
        int s = idx / 96, r = idx % 96;
        int o = r / 16, j = r % 16;
        sW[s * 100 + o * 16 + j] = W[(s * 16 + j) * HID + o];
    }
    __syncthreads();
    int t = blockIdx.x * 256 + threadIdx.x;
    int i = t >> 3;
    int sub = t & 7;
    if (t == 0) g16[N] = make_uint4(0u, 0u, 0u, 0u);    // zero row for sentinel pads
    if (i >= N) return;
    const float4* xr = (const float4*)(x + (size_t)i * NF + sub * 16);
    float4 xv0 = xr[0], xv1 = xr[1], xv2 = xr[2], xv3 = xr[3];
    const float4* wr = (const float4*)(sW + sub * 100);
    float p[HID];
#pragma unroll
    for (int o = 0; o < HID; ++o) {
        float4 w0 = wr[o * 4 + 0], w1 = wr[o * 4 + 1], w2 = wr[o * 4 + 2], w3 = wr[o * 4 + 3];
        p[o] = xv0.x * w0.x + xv0.y * w0.y + xv0.z * w0.z + xv0.w * w0.w
             + xv1.x * w1.x + xv1.y * w1.y + xv1.z * w1.z + xv1.w * w1.w
             + xv2.x * w2.x + xv2.y * w2.y + xv2.z * w2.z + xv2.w * w2.w
             + xv3.x * w3.x + xv3.y * w3.y + xv3.z * w3.z + xv3.w * w3.w;
    }
#pragma unroll
    for (int m = 1; m < 8; m <<= 1) {
#pragma unroll
        for (int o = 0; o < HID; ++o) p[o] += __shfl_xor(p[o], m);
    }
    if (sub == 0) {
        float dv = dinv[i];
        float v[HID];
#pragma unroll
        for (int o = 0; o < HID; ++o) v[o] = dv * p[o];
        g16[i] = packh(v);
    }
}

// ---------------- chunked ELL gather (fp16 rows, fp16 accumulate, padded rows) ----------------
__device__ __forceinline__ void gather8h(int ne, const int* __restrict__ er,
                                         const uint4* __restrict__ g16, int sub,
                                         __half2& a0, __half2& a1, __half2& a2) {
#pragma unroll
    for (int r = 0; r < SLOTS / 32; ++r) {
        int base = r * 32 + sub * 4;
        if (base < ne) {
            int4 q = *(const int4*)(er + base);
            uint4 v0 = g16[q.x];
            uint4 v1 = g16[q.y];
            uint4 v2 = g16[q.z];
            uint4 v3 = g16[q.w];
            addh2(a0, a1, a2, v0);
            addh2(a0, a1, a2, v1);
            addh2(a0, a1, a2, v2);
            addh2(a0, a1, a2, v3);
        }
    }
}

// ---------------- fused: gather + epilogue (+ next matmul), 8 lanes per node ----------------
// PREP=0: gout = dinv * (relu(dinv*(sum+self)+b) @ W)
// PREP=1: gout = dinv *  relu(dinv*(sum+self)+b)
template<int PREP>
__global__ __launch_bounds__(256) void gcn_layer8_kernel(
        const int* __restrict__ cnt, const int* __restrict__ ell,
        const int* __restrict__ ovf_meta, const int* __restrict__ ovf_dst,
        const int* __restrict__ ovf_src, const float* __restrict__ dinv,
        const uint4* __restrict__ gin, uint4* __restrict__ gout,
        const float* __restrict__ W, const float* __restrict__ b, int N) {
    int t = blockIdx.x * 256 + threadIdx.x;
    int i = t >> 3;
    int sub = t & 7;
    if (t == 0) gout[N] = make_uint4(0u, 0u, 0u, 0u);   // keep zero row alive
    if (i >= N) return;
    int n = cnt[i];
    int ne = n < SLOTS ? n : SLOTS;
    const int* er = ell + (size_t)i * SLOTS;
    __half2 a0 = __float2half2_rn(0.f), a1 = a0, a2 = a0;
    gather8h(ne, er, gin, sub, a0, a1, a2);
    // self-loop term, added exactly once across the subgroup
    if (sub == 0) addh2(a0, a1, a2, gin[i]);
    if (n > SLOTS && sub == 2) {  // ~never taken; correct fallback for deg>SLOTS
        int m = ovf_meta[0];
        m = m < OVFCAP ? m : OVFCAP;
        for (int tt = 0; tt < m; ++tt) {
            if (ovf_dst[tt] == i) addh2(a0, a1, a2, gin[ovf_src[tt]]);
        }
    }
    // packed butterfly (all 8 lanes end with the total)
#pragma unroll
    for (int m = 1; m < 8; m <<= 1) {
        a0 = __hadd2(a0, shfl_xor_h2(a0, m));
        a1 = __hadd2(a1, shfl_xor_h2(a1, m));
        a2 = __hadd2(a2, shfl_xor_h2(a2, m));
    }
    if (sub != 0) return;
    float2 f0 = __half22float2(a0), f1 = __half22float2(a1), f2 = __half22float2(a2);
    float acc[HID] = { f0.x, f0.y, f1.x, f1.y, f2.x, f2.y };
    float dv = dinv[i];
    float h[HID];
#pragma unroll
    for (int f = 0; f < HID; ++f) {
        float u = dv * acc[f] + b[f];
        h[f] = u > 0.0f ? u : 0.0f;
    }
    float o[HID];
    if (PREP) {
#pragma unroll
        for (int f = 0; f < HID; ++f) o[f] = dv * h[f];
    } else {
#pragma unroll
        for (int fo = 0; fo < HID; ++fo) {
            float s = 0.0f;
#pragma unroll
            for (int fi = 0; fi < HID; ++fi) s += h[fi] * W[fi * HID + fo];
            o[fo] = dv * s;
        }
    }
    gout[i] = packh(o);
}

// ---------------- pool: gather conv7 + Wf + relu + LDS mean-pool, 8 lanes per node ----------------
__global__ __launch_bounds__(256) void pool_kernel(
        const int* __restrict__ cnt, const int* __restrict__ ell,
        const int* __restrict__ ovf_meta, const int* __restrict__ ovf_dst,
        const int* __restrict__ ovf_src, const float* __restrict__ dinv,
        const uint4* __restrict__ gin, const int* __restrict__ batch,
        const float* __restrict__ Wf, const float* __restrict__ bf,
        float* __restrict__ pooled, float* __restrict__ gcnt, int N) {
    __shared__ float sp[NG * NC];
    __shared__ float sc[NG];
    __shared__ int srange[2];
    for (int k = threadIdx.x; k < NG * NC; k += 256) sp[k] = 0.0f;
    if (threadIdx.x < NG) sc[threadIdx.x] = 0.0f;
    int start = blockIdx.x * 32;           // 32 nodes per block (256 thr / 8)
    int endi = min(start + 32, N) - 1;
    if (threadIdx.x == 0) {
        srange[0] = batch[start];   // batch is sorted
        srange[1] = batch[endi];
    }
    __syncthreads();
    int t = blockIdx.x * 256 + threadIdx.x;
    int i = t >> 3;
    int sub = t & 7;
    if (i < N) {
        int n = cnt[i];
        int ne = n < SLOTS ? n : SLOTS;
        const int* er = ell + (size_t)i * SLOTS;
        __half2 a0 = __float2half2_rn(0.f), a1 = a0, a2 = a0;
        gather8h(ne, er, gin, sub, a0, a1, a2);
        if (sub == 0) addh2(a0, a1, a2, gin[i]);
        if (n > SLOTS && sub == 2) {
            int m = ovf_meta[0];
            m = m < OVFCAP ? m : OVFCAP;
            for (int tt = 0; tt < m; ++tt) {
                if (ovf_dst[tt] == i) addh2(a0, a1, a2, gin[ovf_src[tt]]);
            }
        }
#pragma unroll
        for (int m = 1; m < 8; m <<= 1) {
            a0 = __hadd2(a0, shfl_xor_h2(a0, m));
            a1 = __hadd2(a1, shfl_xor_h2(a1, m));
            a2 = __hadd2(a2, shfl_xor_h2(a2, m));
        }
        if (sub == 0) {
            float2 f0 = __half22float2(a0), f1 = __half22float2(a1), f2 = __half22float2(a2);
            float acc[HID] = { f0.x, f0.y, f1.x, f1.y, f2.x, f2.y };
            float dv = dinv[i];
            float u[HID];
#pragma unroll
            for (int f = 0; f < HID; ++f) u[f] = dv * acc[f];
            int bg = batch[i];
#pragma unroll
            for (int c = 0; c < NC; ++c) {
                float v = bf[c];
#pragma unroll
                for (int f = 0; f < HID; ++f) v += u[f] * Wf[f * NC + c];
                v = v > 0.0f ? v : 0.0f;
                atomicAdd(&sp[bg * NC + c], v);
            }
            atomicAdd(&sc[bg], 1.0f);
        }
    }
    __syncthreads();
    int bmin = srange[0], bmax = srange[1];
    int rows = bmax - bmin + 1;
    for (int k = threadIdx.x; k < rows * NC; k += 256) {
        int r = bmin + k / NC, c = k % NC;
        float v = sp[r * NC + c];
        if (v != 0.0f) atomicAdd(&pooled[r * NC + c], v);
    }
    for (int k = threadIdx.x; k < rows; k += 256) {
        float v = sc[bmin + k];
        if (v != 0.0f) atomicAdd(&gcnt[bmin + k], v);
    }
}

// ---------------- mean + log_softmax ----------------
__global__ void logsm_kernel(const float* __restrict__ pooled, const float* __restrict__ gcnt,
                             float* __restrict__ out) {
    int gidx = threadIdx.x;
    if (gidx >= NG) return;
    float c = gcnt[gidx];
    c = c > 1.0f ? c : 1.0f;
    float v[NC];
    float m = -1e30f;
#pragma unroll
    for (int k = 0; k < NC; ++k) {
        v[k] = pooled[gidx * NC + k] / c;
        m = v[k] > m ? v[k] : m;
    }
    float s = 0.0f;
#pragma unroll
    for (int k = 0; k < NC; ++k) s += expf(v[k] - m);
    float ls = logf(s);
#pragma unroll
    for (int k = 0; k < NC; ++k) out[gidx * NC + k] = v[k] - m - ls;
}

extern "C" void kernel_launch(void* const* d_in, const int* in_sizes, int n_in,
                              void* d_out, int out_size, void* d_ws, size_t ws_size,
                              hipStream_t stream) {
    const float* x     = (const float*)d_in[0];
    const int*   ei    = (const int*)d_in[1];
    const int*   batch = (const int*)d_in[2];
    const float* W[7];
    const float* b[7];
    for (int l = 0; l < 7; ++l) {
        W[l] = (const float*)d_in[3 + 2 * l];
        b[l] = (const float*)d_in[4 + 2 * l];
    }
    const int N = in_sizes[2];
    const int E = in_sizes[1] / 2;
    const int nbk  = (N + BKT_NODES - 1) >> BKT_SH;   // 512-node buckets
    const int nsub = (N + SUB_NODES - 1) >> SUB_SH;   // 128-node subranges
    const int* src = ei;
    const int* dst = ei + E;
    float* out = (float*)d_out;

    // workspace layout (16B-aligned blocks)
    char* wp = (char*)d_ws;
    int* bucket_cursor = (int*)wp;  wp += (size_t)NBK_MAX * 4;
    int* ovf_meta  = (int*)wp;      wp += 16;
    int* bovf_meta = (int*)wp;      wp += 16;   // metas contiguous with cursor -> one memset
    int* ovf_dst   = (int*)wp;      wp += OVFCAP * 4;
    int* ovf_src   = (int*)wp;      wp += OVFCAP * 4;
    int2* bovf     = (int2*)wp;     wp += (size_t)BOVFCAP * 8;
    int* cnt       = (int*)wp;      wp += (((size_t)N * 4 + 15) & ~15ull);
    float* dinv    = (float*)wp;    wp += (((size_t)N * 4 + 15) & ~15ull);
    uint4* g_a     = (uint4*)wp;    wp += (size_t)(N + 1) * 16;   // +1: zero row for pads
    uint4* g_b     = (uint4*)wp;    wp += (size_t)(N + 1) * 16;
    float* pooled  = (float*)wp;    wp += NG * NC * 4;
    float* gcnt    = (float*)wp;    wp += (((size_t)NG * 4 + 15) & ~15ull);
    int* ell       = (int*)wp;      wp += (size_t)N * SLOTS * 4;
    unsigned int* bucket_arr = (unsigned int*)wp;  wp += (size_t)nbk * BCAP * 4;

    hipMemsetAsync(bucket_cursor, 0, (size_t)NBK_MAX * 4 + 32, stream);  // + both metas
    hipMemsetAsync(pooled, 0, (NG * NC + NG) * sizeof(float), stream);

    const int BT = 256;
    int bn8 = ((size_t)N * 8 + BT - 1) / BT;
    int bp1 = (E + EPB - 1) / EPB;

    bucket_scatter_kernel<<<bp1, BT, 0, stream>>>(src, dst, E, nbk, bucket_cursor,
                                                  bucket_arr, bovf_meta, bovf);
    ell_build_kernel<<<nsub, BT, 0, stream>>>(bucket_arr, bucket_cursor, bovf_meta, bovf,
                                              ell, cnt, dinv, ovf_meta, ovf_dst, ovf_src, N);

    layer1_kernel<<<bn8, BT, 0, stream>>>(x, W[0], dinv, g_a, N);

    // 5 mid layers: (b1,W2) .. (b5,W6), alternating g buffers
    gcn_layer8_kernel<0><<<bn8, BT, 0, stream>>>(cnt, ell, ovf_meta, ovf_dst, ovf_src, dinv, g_a, g_b, W[1], b[0], N);
    gcn_layer8_kernel<0><<<bn8, BT, 0, stream>>>(cnt, ell, ovf_meta, ovf_dst, ovf_src, dinv, g_b, g_a, W[2], b[1], N);
    gcn_layer8_kernel<0><<<bn8, BT, 0, stream>>>(cnt, ell, ovf_meta, ovf_dst, ovf_src, dinv, g_a, g_b, W[3], b[2], N);
    gcn_layer8_kernel<0><<<bn8, BT, 0, stream>>>(cnt, ell, ovf_meta, ovf_dst, ovf_src, dinv, g_b, g_a, W[4], b[3], N);
    gcn_layer8_kernel<0><<<bn8, BT, 0, stream>>>(cnt, ell, ovf_meta, ovf_dst, ovf_src, dinv, g_a, g_b, W[5], b[4], N);
    // layer 6 epilogue (b6), no next W
    gcn_layer8_kernel<1><<<bn8, BT, 0, stream>>>(cnt, ell, ovf_meta, ovf_dst, ovf_src, dinv, g_b, g_a, nullptr, b[5], N);
    // conv7 gather + Wf + bf + relu + pool
    pool_kernel<<<bn8, BT, 0, stream>>>(cnt, ell, ovf_meta, ovf_dst, ovf_src, dinv, g_a, batch, W[6], b[6], pooled, gcnt, N);
    logsm_kernel<<<1, 64, 0, stream>>>(pooled, gcnt, out);
}